// Round 1
// 337.920 us; speedup vs baseline: 1.0286x; 1.0286x over previous
//
#include <hip/hip_runtime.h>

#define NQ 8
#define KCODES 1024
#define D 64
#define CHUNK 64             // prep_cb granule (64-code chunks, ws_cb layout unchanged)
#define NCHUNK 16
#define CH32 32              // staging chunk: 32 codes, double-buffered
#define NGI (NQ * 32)        // 256 staged chunks total
#define TPB 256
#define TOKPB 64             // tokens per block = 2 groups x 32
#define BIAS 96.0f

using short8 = __attribute__((ext_vector_type(8))) short;
using f32x4  = __attribute__((ext_vector_type(4))) float;

#define GLOBAL_AS __attribute__((address_space(1)))
#define LDS_AS    __attribute__((address_space(3)))

static __device__ __forceinline__ unsigned bf16_rne_bits(float f) {
    unsigned u = __float_as_uint(f);
    return (u + 0x7fffu + ((u >> 16) & 1u)) >> 16;   // bf16 RNE bit pattern
}
static __device__ __forceinline__ unsigned umn(unsigned a, unsigned b) { return a < b ? a : b; }
static __device__ __forceinline__ unsigned umx(unsigned a, unsigned b) { return a > b ? a : b; }
// true 3-input median in one VOP3 (no clang builtin for u32 med3 -> inline asm)
static __device__ __forceinline__ unsigned umed3(unsigned a, unsigned b, unsigned c) {
    unsigned d;
    asm("v_med3_u32 %0, %1, %2, %3" : "=v"(d) : "v"(a), "v"(b), "v"(c));
    return d;
}

// ---------------- prologue 1: split NEGATED codebook into bf16 hi/lo granules ----------------
// ws_cb layout: [q][ch16][plane16][code64], plane = term*8 + kt*4 + g. Stores -c.
__global__ __launch_bounds__(256) void prep_cb(const float* __restrict__ cb,
                                               int4* __restrict__ ws_cb) {
    int id = blockIdx.x * 256 + threadIdx.x;       // 0 .. 131071
    int n_rel = id & 63;
    int plane = (id >> 6) & 15;
    int ch    = (id >> 10) & 15;
    int q     = id >> 14;
    int g = plane & 3, kt = (plane >> 2) & 1, term = plane >> 3;
    int n = ch * CHUNK + n_rel;
    const float* src = cb + ((size_t)(q * KCODES + n)) * D + kt * 32 + g * 8;
    union { short s[8]; int4 v; } u;
    #pragma unroll
    for (int j = 0; j < 8; ++j) {
        float f = -src[j];                         // NEGATED
        unsigned hb = bf16_rne_bits(f);
        if (term == 0) {
            u.s[j] = (short)hb;
        } else {
            float lo = f - __uint_as_float(hb << 16);
            u.s[j] = (short)bf16_rne_bits(lo);
        }
    }
    ws_cb[id] = u.v;
}

// ---------------- prologue 2: c_sq exact (refine) + seed (csq/2 + BIAS, approx) ----------------
__global__ __launch_bounds__(256) void prep_csq(const float* __restrict__ cb,
                                                float* __restrict__ ws_csq,
                                                float* __restrict__ ws_csqh) {
    int id = blockIdx.x * 256 + threadIdx.x;       // 0 .. 8191
    const float* c = cb + (size_t)id * D;
    float s0 = 0.f, s1 = 0.f, s2 = 0.f, s3 = 0.f;
    #pragma unroll
    for (int j = 0; j < 16; ++j) {
        s0 = fmaf(c[4*j+0], c[4*j+0], s0);
        s1 = fmaf(c[4*j+1], c[4*j+1], s1);
        s2 = fmaf(c[4*j+2], c[4*j+2], s2);
        s3 = fmaf(c[4*j+3], c[4*j+3], s3);
    }
    float cs = (s0 + s1) + (s2 + s3);
    ws_csq[id]  = cs;                // exact, refine comparator (bit-identical to prior rounds)
    ws_csqh[id] = 0.5f * cs + BIAS;  // approx seed: acc = seed - dot (always > 0)
}

// ---------------- main kernel ----------------
// Wave (group, half) = 32 tokens x 16 codes of each 32-chunk. 4 blocks/CU, 16 waves/CU.
// Double-buffered 8KB staging chunks: prefetch gi+1 after the barrier, compute gi from the
// other buffer -> the compiler's vmcnt(0)-before-barrier drain lands on warm loads.
#define CHUNK_BODY(BUF, GI)                                                               \
  {                                                                                       \
    __syncthreads();                                                                      \
    if ((GI) + 1 < NGI) {                                                                 \
      const int gin = (GI) + 1;                                                           \
      const int qn = gin >> 5, chn = gin & 31;                                            \
      const int4* srcn = ws_cb + (((qn * 16 + (chn >> 1)) << 10) + ((chn & 1) << 5));     \
      _Pragma("unroll")                                                                   \
      for (int t = 0; t < 2; ++t) {                                                       \
        const int id = t * 256 + tid;                                                     \
        __builtin_amdgcn_global_load_lds(                                                 \
            (const GLOBAL_AS unsigned int*)(srcn + ((id >> 5) << 6) + (id & 31)),         \
            (LDS_AS unsigned int*)((LDS_AS char*)&lds_stage[(BUF) ^ 1][0] + id * 16),     \
            16, 0, 0);                                                                    \
      }                                                                                   \
      if (tid < CH32) {                                                                   \
        __builtin_amdgcn_global_load_lds(                                                 \
            (const GLOBAL_AS unsigned int*)(ws_csqh + qn * KCODES + chn * CH32 + tid),    \
            (LDS_AS unsigned int*)(&lds_csqh[(BUF) ^ 1][tid]), 4, 0, 0);                  \
      }                                                                                   \
    }                                                                                     \
    const char* bb = (const char*)&lds_stage[(BUF)][0] + bB;                              \
    short8 bh0 = *(const short8*)(bb);                                                    \
    short8 bh1 = *(const short8*)(bb + 2048);                                             \
    short8 bl0 = *(const short8*)(bb + 4096);                                             \
    short8 bl1 = *(const short8*)(bb + 6144);                                             \
    const float sd = lds_csqh[(BUF)][half * 16 + c];                                      \
    const unsigned codev = (unsigned)((((GI) & 31) << 5) + (half << 4) + c);              \
    _Pragma("unroll")                                                                     \
    for (int s = 0; s < 2; ++s) {                                                         \
      f32x4 acc = {sd, sd, sd, sd};                                                       \
      acc = __builtin_amdgcn_mfma_f32_16x16x32_bf16(ah0[s], bh0, acc, 0, 0, 0);           \
      acc = __builtin_amdgcn_mfma_f32_16x16x32_bf16(ah1[s], bh1, acc, 0, 0, 0);           \
      acc = __builtin_amdgcn_mfma_f32_16x16x32_bf16(al0[s], bh0, acc, 0, 0, 0);           \
      acc = __builtin_amdgcn_mfma_f32_16x16x32_bf16(ah0[s], bl0, acc, 0, 0, 0);           \
      acc = __builtin_amdgcn_mfma_f32_16x16x32_bf16(al1[s], bh1, acc, 0, 0, 0);           \
      acc = __builtin_amdgcn_mfma_f32_16x16x32_bf16(ah1[s], bl1, acc, 0, 0, 0);           \
      _Pragma("unroll")                                                                   \
      for (int r = 0; r < 4; ++r) {                                                       \
        const unsigned p = (__float_as_uint(acc[r]) & 0xFFFFFC00u) | codev;               \
        const unsigned t1o = T1[s][r], t2o = T2[s][r];                                    \
        T1[s][r] = umn(t1o, p);            /* given t1o<=t2o<=t3o these med3s are */      \
        T2[s][r] = umed3(t1o, t2o, p);     /* bit-identical to min(T2,max(T1,p)) / */     \
        T3[s][r] = umed3(t2o, T3[s][r], p);/* min(T3,max(T2,p)) at 1 VOP3 each    */      \
      }                                                                                   \
    }                                                                                     \
  }

__global__ __launch_bounds__(TPB, 4) void rvq_mfma(
    const float* __restrict__ x,
    const float* __restrict__ cb,
    const int4* __restrict__ ws_cb,
    const float* __restrict__ ws_csq,
    float* __restrict__ out)
{
    __shared__ __align__(16) int4  lds_stage[2][512];      // 2 x 8 KB codebook sub-chunk
    __shared__ __align__(16) float lds_resid[TOKPB * 68];  // 17408 B persistent residual
    __shared__ float    lds_csqh[2][CH32];                 // 2 x 128 B
    __shared__ unsigned lds_cand[2][TOKPB * 3];            // 1536 B packed top-3 per half
    __shared__ int      lds_pick[TOKPB];                   // 256 B

    const int tid   = threadIdx.x;
    const int lane  = tid & 63;
    const int wave  = tid >> 6;          // 0..3
    const int group = wave >> 1;         // 0..1 (token group of 32)
    const int half  = wave & 1;          // code half (16 codes of the 32-chunk)
    const int g     = lane >> 4;         // quad
    const int c     = lane & 15;
    const int tok0  = blockIdx.x * TOKPB;
    const float* ws_csqh = ws_csq + 8192;

    // ---- prefetch very first chunk (gi=0) into buf 0, overlapping residual init ----
    {
        #pragma unroll
        for (int t = 0; t < 2; ++t) {
            const int id = t * 256 + tid;
            __builtin_amdgcn_global_load_lds(
                (const GLOBAL_AS unsigned int*)(ws_cb + ((id >> 5) << 6) + (id & 31)),
                (LDS_AS unsigned int*)((LDS_AS char*)&lds_stage[0][0] + id * 16), 16, 0, 0);
        }
        if (tid < CH32) {
            __builtin_amdgcn_global_load_lds(
                (const GLOBAL_AS unsigned int*)(ws_csqh + tid),
                (LDS_AS unsigned int*)(&lds_csqh[0][tid]), 4, 0, 0);
        }
    }

    // ---- init: residual = x, into LDS (4 threads per token) ----
    {
        const int t = tid >> 2, part = tid & 3;
        const float4* xp = (const float4*)(x + (size_t)(tok0 + t) * D + part * 16);
        float4* rr = (float4*)(lds_resid + t * 68 + part * 16);
        #pragma unroll
        for (int k2 = 0; k2 < 4; ++k2) rr[k2] = xp[k2];
    }

    // static LDS byte offset for B-fragment reads (compile-time ds_read offsets per buf)
    const int bB = (g << 9) + ((half * 16 + c) << 4);

    for (int q = 0; q < NQ; ++q) {
        __syncthreads();   // residual init / previous q's update visible

        // ---- A-split for the group's two 16-token sub-tiles ----
        short8 ah0[2], ah1[2], al0[2], al1[2];
        #pragma unroll
        for (int s = 0; s < 2; ++s) {
            const float* rr = lds_resid + (group * 32 + s * 16 + c) * 68;
            float4 f0 = *(const float4*)(rr + 8 * g);
            float4 f1 = *(const float4*)(rr + 8 * g + 4);
            float4 f2 = *(const float4*)(rr + 32 + 8 * g);
            float4 f3 = *(const float4*)(rr + 36 + 8 * g);
            const float* v0 = (const float*)&f0;
            const float* v1 = (const float*)&f1;
            const float* v2 = (const float*)&f2;
            const float* v3 = (const float*)&f3;
            #pragma unroll
            for (int j = 0; j < 4; ++j) {
                float a = v0[j], b = v1[j], e = v2[j], f = v3[j];
                unsigned ha = bf16_rne_bits(a);
                unsigned hb = bf16_rne_bits(b);
                unsigned he = bf16_rne_bits(e);
                unsigned hf = bf16_rne_bits(f);
                ah0[s][j]   = (short)ha;  ah0[s][4+j] = (short)hb;
                ah1[s][j]   = (short)he;  ah1[s][4+j] = (short)hf;
                al0[s][j]   = (short)bf16_rne_bits(a - __uint_as_float(ha << 16));
                al0[s][4+j] = (short)bf16_rne_bits(b - __uint_as_float(hb << 16));
                al1[s][j]   = (short)bf16_rne_bits(e - __uint_as_float(he << 16));
                al1[s][4+j] = (short)bf16_rne_bits(f - __uint_as_float(hf << 16));
            }
        }

        // packed top-3 per (sub-tile, row) — ascending u32
        unsigned T1[2][4], T2[2][4], T3[2][4];
        #pragma unroll
        for (int s = 0; s < 2; ++s)
            #pragma unroll
            for (int r = 0; r < 4; ++r) { T1[s][r] = 0xFFFFFFFFu; T2[s][r] = 0xFFFFFFFFu; T3[s][r] = 0xFFFFFFFFu; }

        // ---- chunk loop: 16 pairs of double-buffered 32-code chunks ----
        for (int cp = 0; cp < 16; ++cp) {
            const int gi0 = (q << 5) + (cp << 1);
            CHUNK_BODY(0, gi0);
            CHUNK_BODY(1, gi0 + 1);
        }

        // ---- cross-lane top-3 merge over the 16 c-lanes ----
        #pragma unroll
        for (int st = 1; st <= 8; st <<= 1) {
            #pragma unroll
            for (int s = 0; s < 2; ++s) {
                #pragma unroll
                for (int r = 0; r < 4; ++r) {
                    unsigned o1 = (unsigned)__shfl_xor((int)T1[s][r], st);
                    unsigned o2 = (unsigned)__shfl_xor((int)T2[s][r], st);
                    unsigned o3 = (unsigned)__shfl_xor((int)T3[s][r], st);
                    unsigned x1 = umn(T1[s][r], o1), y1 = umx(T1[s][r], o1);
                    unsigned x2 = umn(T2[s][r], o2), y2 = umx(T2[s][r], o2);
                    unsigned x3 = umn(T3[s][r], o3);
                    T1[s][r] = x1;
                    T3[s][r] = umed3(y1, x2, umn(y2, x3));
                    T2[s][r] = umn(y1, x2);
                }
            }
        }

        // ---- publish per-half candidates ----
        if (c == 0) {
            #pragma unroll
            for (int s = 0; s < 2; ++s)
                #pragma unroll
                for (int r = 0; r < 4; ++r) {
                    const int idx = (group * 32 + s * 16 + g * 4 + r) * 3;
                    lds_cand[half][idx + 0] = T1[s][r];
                    lds_cand[half][idx + 1] = T2[s][r];
                    lds_cand[half][idx + 2] = T3[s][r];
                }
        }
        __syncthreads();

        // ---- cross-half merge + ALWAYS-ON exact refinement (each wave: 16 tokens) ----
        {
            const int t4  = lane >> 2;          // token within sub-tile
            const int sel = lane & 3;           // candidate slot (3 duplicates slot 2)
            const int row = group * 32 + half * 16 + t4;
            unsigned a1 = lds_cand[0][row * 3 + 0];
            unsigned a2 = lds_cand[0][row * 3 + 1];
            unsigned a3 = lds_cand[0][row * 3 + 2];
            unsigned b1 = lds_cand[1][row * 3 + 0];
            unsigned b2 = lds_cand[1][row * 3 + 1];
            unsigned b3 = lds_cand[1][row * 3 + 2];
            unsigned x1 = umn(a1, b1), y1 = umx(a1, b1);
            unsigned x2 = umn(a2, b2), y2 = umx(a2, b2);
            unsigned x3 = umn(a3, b3);
            unsigned m1 = x1;
            unsigned m2 = umn(y1, x2);
            unsigned m3 = umed3(y1, x2, umn(y2, x3));
            const unsigned psel = (sel == 0) ? m1 : ((sel == 1) ? m2 : m3);
            const int cd = (int)(psel & 1023u);

            // exact fp32 distance, bit-identical comparator arithmetic to prior rounds
            const float4* rrv = (const float4*)(lds_resid + row * 68);
            const float4* cpv = (const float4*)(cb + ((size_t)(q * KCODES + cd)) * D);
            float ax = 0.f, ay = 0.f, az = 0.f, aw = 0.f;
            #pragma unroll
            for (int j = 0; j < 16; ++j) {
                float4 rv = rrv[j];
                float4 cv = cpv[j];
                ax = fmaf(rv.x, cv.x, ax);
                ay = fmaf(rv.y, cv.y, ay);
                az = fmaf(rv.z, cv.z, az);
                aw = fmaf(rv.w, cv.w, aw);
            }
            float dot = (ax + ay) + (az + aw);
            float dd = fmaf(dot, -2.0f, ws_csq[q * KCODES + cd]);

            const int base = lane & ~3;
            float d0 = __shfl(dd, base);
            float d1 = __shfl(dd, base + 1);
            float d2 = __shfl(dd, base + 2);
            int cc0 = (int)(m1 & 1023u);
            int cc1 = (int)(m2 & 1023u);
            int cc2 = (int)(m3 & 1023u);
            float db = d0; int pick = cc0;
            if (d1 < db || (d1 == db && cc1 < pick)) { db = d1; pick = cc1; }
            if (d2 < db || (d2 == db && cc2 < pick)) { db = d2; pick = cc2; }
            if (sel == 0) lds_pick[row] = pick;
        }
        __syncthreads();

        // ---- residual update in LDS: resid -= cb[q][ifin] (4 threads per token) ----
        {
            const int t = tid >> 2, part = tid & 3;
            const int ifin = lds_pick[t];
            const float4* cp = (const float4*)(cb + ((size_t)(q * KCODES + ifin)) * D + part * 16);
            float4* rr = (float4*)(lds_resid + t * 68 + part * 16);
            #pragma unroll
            for (int k2 = 0; k2 < 4; ++k2) {
                float4 rv = rr[k2], cv = cp[k2];
                rv.x -= cv.x; rv.y -= cv.y; rv.z -= cv.z; rv.w -= cv.w;
                rr[k2] = rv;
            }
        }
    }

    // ---- epilogue: out = x - residual_final (4 threads per token) ----
    __syncthreads();
    {
        const int t = tid >> 2, part = tid & 3;
        const float4* xp = (const float4*)(x + (size_t)(tok0 + t) * D + part * 16);
        const float4* rr = (const float4*)(lds_resid + t * 68 + part * 16);
        float4* op = (float4*)(out + (size_t)(tok0 + t) * D + part * 16);
        #pragma unroll
        for (int k2 = 0; k2 < 4; ++k2) {
            float4 xv = xp[k2], rv = rr[k2];
            float4 o;
            o.x = xv.x - rv.x; o.y = xv.y - rv.y;
            o.z = xv.z - rv.z; o.w = xv.w - rv.w;
            op[k2] = o;
        }
    }
}

extern "C" void kernel_launch(void* const* d_in, const int* in_sizes, int n_in,
                              void* d_out, int out_size, void* d_ws, size_t ws_size,
                              hipStream_t stream) {
    const float* x  = (const float*)d_in[0];
    const float* cb = (const float*)d_in[1];
    float* out = (float*)d_out;

    int4*  ws_cb   = (int4*)d_ws;                                      // 2 MB
    float* ws_csq  = (float*)((char*)d_ws + (size_t)2 * 1024 * 1024);  // 32 KB exact
    float* ws_csqh = ws_csq + 8192;                                    // 32 KB seed (= ws_csq+8192)

    prep_cb <<<512, 256, 0, stream>>>(cb, ws_cb);
    prep_csq<<< 32, 256, 0, stream>>>(cb, ws_csq, ws_csqh);

    const int n_tokens = in_sizes[0] / D;            // 65536
    const int grid = n_tokens / TOKPB;               // 1024 blocks
    rvq_mfma<<<grid, TPB, 0, stream>>>(x, cb, ws_cb, ws_csq, out);
}